// Round 3
// baseline (87.343 us; speedup 1.0000x reference)
//
#include <hip/hip_runtime.h>

// ForexPrep: per row (T=8192): p = diff(x)/x[:-1]; scale = max|p| (row);
// pn = p/scale; ma = 7-window moving average; out[b,j] = {ma(j), x(j)}.
// x (4096, 8192) f32 -> out (4096, 8185, 2) f32.
//
// R2: phase-1 max fused into register staging (no LDS reads); phase 2 does
// 4 outputs/lane with vectorized LDS reads and 2 adjacent dwordx4 stores.

constexpr int T_LEN = 8192;
constexpr int GAP_  = 7;
constexpr int OUTW  = T_LEN - GAP_;   // 8185
constexpr int NTHR  = 256;
constexpr int QUADS = 2046;           // 4-output groups per row (8184 outputs + 1 leftover)

__global__ __launch_bounds__(NTHR)
void forex_prep_kernel(const float* __restrict__ x, float* __restrict__ out,
                       int n_rows) {
    const int row = blockIdx.x;
    if (row >= n_rows) return;
    const int t = threadIdx.x;

    __shared__ float xs[T_LEN];        // 32 KB row stage
    __shared__ float red[NTHR / 64];

    const float* __restrict__ xr = x + (size_t)row * T_LEN;

    // ---- Stage row (coalesced float4) and compute max|p| from registers.
    float4 v[8];
#pragma unroll
    for (int i = 0; i < 8; ++i) {
        const int e = (i * NTHR + t) * 4;
        v[i] = *reinterpret_cast<const float4*>(xr + e);
        *reinterpret_cast<float4*>(xs + e) = v[i];
    }
    float m = 0.0f;
#pragma unroll
    for (int i = 0; i < 8; ++i) {
        const float xn = __shfl_down(v[i].x, 1, 64);   // next lane's first x
        const float p0 = fmaf(v[i].y, __builtin_amdgcn_rcpf(v[i].x), -1.0f);
        const float p1 = fmaf(v[i].z, __builtin_amdgcn_rcpf(v[i].y), -1.0f);
        const float p2 = fmaf(v[i].w, __builtin_amdgcn_rcpf(v[i].z), -1.0f);
        m = fmaxf(m, fmaxf(fabsf(p0), fmaxf(fabsf(p1), fabsf(p2))));
        if ((t & 63) != 63) {          // wave-seam p handled later from LDS
            const float p3 = fmaf(xn, __builtin_amdgcn_rcpf(v[i].w), -1.0f);
            m = fmaxf(m, fabsf(p3));
        }
    }
    __syncthreads();                   // xs ready
    // 31 wave-seam p's: k = 256*t + 255 (k=8191 excluded — not a valid p).
    if (t < 31) {
        const int k = 256 * t + 255;
        const float pk = fmaf(xs[k + 1], __builtin_amdgcn_rcpf(xs[k]), -1.0f);
        m = fmaxf(m, fabsf(pk));
    }
#pragma unroll
    for (int off = 32; off > 0; off >>= 1)
        m = fmaxf(m, __shfl_xor(m, off, 64));
    if ((t & 63) == 0) red[t >> 6] = m;
    __syncthreads();
    const float scale = fmaxf(fmaxf(red[0], red[1]), fmaxf(red[2], red[3]));
    const float inv = __builtin_amdgcn_rcpf(scale * (float)GAP_);  // 1/(7*scale)

    // ---- Phase 2: 4 outputs per lane; vector LDS reads; 2 aligned dwordx4 stores.
    const int s = row & 1;             // alignment shift (out row base ≡ 8 mod 16 for odd rows)
    float* __restrict__ ob = out + (size_t)row * (OUTW * 2);
    const float4* xs4 = reinterpret_cast<const float4*>(xs);
    const float2* xs2 = reinterpret_cast<const float2*>(xs);

#pragma unroll
    for (int i = 0; i < 8; ++i) {
        const int g = i * NTHR + t;    // quad index; j = s + 4g, outputs j..j+3
        if (g < QUADS) {
            float xv[11];              // xv[e] = xs[j+e], e=0..10 (static idx only)
            if (s == 0) {
                const float4 a0 = xs4[g];
                const float4 a1 = xs4[g + 1];
                const float2 b  = xs2[2 * g + 4];
                const float  c  = xs[4 * g + 10];
                xv[0]=a0.x; xv[1]=a0.y; xv[2]=a0.z; xv[3]=a0.w;
                xv[4]=a1.x; xv[5]=a1.y; xv[6]=a1.z; xv[7]=a1.w;
                xv[8]=b.x;  xv[9]=b.y;  xv[10]=c;
            } else {
                const float4 a0 = xs4[g];
                const float4 a1 = xs4[g + 1];
                const float4 a2 = xs4[g + 2];
                xv[0]=a0.y; xv[1]=a0.z; xv[2]=a0.w;
                xv[3]=a1.x; xv[4]=a1.y; xv[5]=a1.z; xv[6]=a1.w;
                xv[7]=a2.x; xv[8]=a2.y; xv[9]=a2.z; xv[10]=a2.w;
            }
            float p[10];
#pragma unroll
            for (int e = 0; e < 10; ++e)
                p[e] = fmaf(xv[e + 1], __builtin_amdgcn_rcpf(xv[e]), -1.0f);
            const float w0 = ((p[0]+p[1]) + (p[2]+p[3])) + ((p[4]+p[5]) + p[6]);
            const float w1 = w0 - p[0] + p[7];
            const float w2 = w1 - p[1] + p[8];
            const float w3 = w2 - p[2] + p[9];
            const int j2 = 2 * (s + 4 * g);   // float offset in ob; 16B aligned
            *reinterpret_cast<float4*>(ob + j2) =
                make_float4(w0 * inv, xv[0], w1 * inv, xv[1]);
            *reinterpret_cast<float4*>(ob + j2 + 4) =
                make_float4(w2 * inv, xv[2], w3 * inv, xv[3]);
        }
    }

    // ---- Leftover single output (j=8184 for even rows, j=0 for odd rows).
    if (t == 0) {
        const int j = s ? 0 : (OUTW - 1);
        float w = 0.0f;
#pragma unroll
        for (int e = 0; e < GAP_; ++e)
            w += fmaf(xs[j + e + 1], __builtin_amdgcn_rcpf(xs[j + e]), -1.0f);
        *reinterpret_cast<float2*>(ob + 2 * j) = make_float2(w * inv, xs[j]);
    }
}

extern "C" void kernel_launch(void* const* d_in, const int* in_sizes, int n_in,
                              void* d_out, int out_size, void* d_ws, size_t ws_size,
                              hipStream_t stream) {
    const float* x = (const float*)d_in[0];
    float* out = (float*)d_out;
    const int n_rows = in_sizes[0] / T_LEN;   // 4096
    dim3 grid(n_rows), block(NTHR);
    hipLaunchKernelGGL(forex_prep_kernel, grid, block, 0, stream, x, out, n_rows);
}

// Round 4
// 83.537 us; speedup vs baseline: 1.0456x; 1.0456x over previous
//
#include <hip/hip_runtime.h>

// ForexPrep: per row (T=8192): p = diff(x)/x[:-1]; scale = max|p| (row);
// pn = p/scale; ma = 7-window moving average; out[b,j] = {ma(j), x(j)}.
// x (4096, 8192) f32 -> out (4096, 8185, 2) f32.
//
// R3: register rolling-window pipeline (thread owns 16 consecutive outputs,
// 1.4 rcp/output) + LDS pad-33 transpose tile so global stores are fully
// dense float2 (alignment-proof, no odd/even-row special case).

constexpr int T_LEN = 8192;
constexpr int GAP_  = 7;
constexpr int OUTW  = T_LEN - GAP_;     // 8185
constexpr int NP    = T_LEN - 1;        // 8191
constexpr int NTHR  = 512;
constexpr int CH    = 16;               // outputs per thread
constexpr int ROWF  = OUTW * 2;         // 16370 floats per output row
constexpr int SEGF  = 8192;             // floats per segment (4096 outputs)

__global__ __launch_bounds__(NTHR)
void forex_prep_kernel(const float* __restrict__ x, float* __restrict__ out,
                       int n_rows) {
    const int row = blockIdx.x;
    if (row >= n_rows) return;
    const int t = threadIdx.x;

    __shared__ float tile[256 * 33];    // 33 KB transpose tile (pad-1 per 32)
    __shared__ float red[NTHR / 64];

    const float* __restrict__ xr = x + (size_t)row * T_LEN;
    const int base = CH * t;

    // ---- Load x[base .. base+23] into registers (6x float4; OOB -> 1.0f).
    float xv[CH + GAP_ + 1];
#pragma unroll
    for (int q = 0; q < 6; ++q) {
        const int e = base + 4 * q;
        if (e + 3 < T_LEN) {
            const float4 v = *reinterpret_cast<const float4*>(xr + e);
            xv[4*q+0] = v.x; xv[4*q+1] = v.y; xv[4*q+2] = v.z; xv[4*q+3] = v.w;
        } else {
#pragma unroll
            for (int e2 = 0; e2 < 4; ++e2)
                xv[4*q+e2] = (e + e2 < T_LEN) ? xr[e + e2] : 1.0f;
        }
    }

    // ---- p[k] = x[base+k+1]/x[base+k] - 1, zeroed where invalid.
    float p[CH + GAP_ - 1];             // 22
#pragma unroll
    for (int k = 0; k < CH + GAP_ - 1; ++k) {
        const float pk = fmaf(xv[k + 1], __builtin_amdgcn_rcpf(xv[k]), -1.0f);
        p[k] = (base + k < NP) ? pk : 0.0f;
    }

    // ---- Block max of |p| over each thread's own share (k = 0..15).
    float m = 0.0f;
#pragma unroll
    for (int k = 0; k < CH; ++k) m = fmaxf(m, fabsf(p[k]));
#pragma unroll
    for (int off = 32; off > 0; off >>= 1)
        m = fmaxf(m, __shfl_xor(m, off, 64));
    if ((t & 63) == 0) red[t >> 6] = m;
    __syncthreads();
    float scale = red[0];
#pragma unroll
    for (int wv = 1; wv < NTHR / 64; ++wv) scale = fmaxf(scale, red[wv]);
    const float inv = __builtin_amdgcn_rcpf(scale * (float)GAP_);  // 1/(7*scale)

    // ---- Rolling 7-window sums -> ma[0..15] in registers.
    float ma[CH];
    float w = ((p[0] + p[1]) + (p[2] + p[3])) + ((p[4] + p[5]) + p[6]);
    ma[0] = w * inv;
#pragma unroll
    for (int k = 1; k < CH; ++k) {
        w += p[k + GAP_ - 1] - p[k - 1];
        ma[k] = w * inv;
    }

    // ---- Two segments: transpose through LDS, then dense float2 stores.
    const int my_seg = t >> 8;          // threads 0..255 own outputs [0,4096)
    const int u = t & 255;
    float* __restrict__ orow = out + (size_t)row * ROWF;

#pragma unroll
    for (int seg = 0; seg < 2; ++seg) {
        if (my_seg == seg) {
            float* tb = tile + 33 * u;  // bank = (u + c) % 32: conflict-free
#pragma unroll
            for (int k = 0; k < CH; ++k) {
                tb[2*k]     = ma[k];
                tb[2*k + 1] = xv[k];
            }
        }
        __syncthreads();                // tile ready
        const int nf = (seg == 0) ? SEGF : (ROWF - SEGF);   // 8192 / 8178
        float* __restrict__ gb = orow + seg * SEGF;
#pragma unroll
        for (int q = 0; q < 8; ++q) {
            const int L = (q * NTHR + t) * 2;   // dense even offsets
            if (L < nf) {
                const int Lp = L + (L >> 5);    // pad-1 per 32 floats
                *reinterpret_cast<float2*>(gb + L) =
                    make_float2(tile[Lp], tile[Lp + 1]);
            }
        }
        if (seg == 0) __syncthreads();  // copy done before seg-1 overwrite
    }
}

extern "C" void kernel_launch(void* const* d_in, const int* in_sizes, int n_in,
                              void* d_out, int out_size, void* d_ws, size_t ws_size,
                              hipStream_t stream) {
    const float* x = (const float*)d_in[0];
    float* out = (float*)d_out;
    const int n_rows = in_sizes[0] / T_LEN;   // 4096
    dim3 grid(n_rows), block(NTHR);
    hipLaunchKernelGGL(forex_prep_kernel, grid, block, 0, stream, x, out, n_rows);
}

// Round 5
// 73.512 us; speedup vs baseline: 1.1881x; 1.1364x over previous
//
#include <hip/hip_runtime.h>

// ForexPrep: per row (T=8192): p = diff(x)/x[:-1]; scale = max|p| (row);
// pn = p/scale; ma = 7-window moving average; out[b,j] = {ma(j), x(j)}.
// x (4096, 8192) f32 -> out (4096, 8185, 2) f32.
//
// R4 = R3 (register rolling window + LDS transpose for dense stores) with
// NONTEMPORAL output stores: output is write-once/never-read, so `nt` keeps
// it from evicting the (L3-resident, 134 MB) input between graph replays.

constexpr int T_LEN = 8192;
constexpr int GAP_  = 7;
constexpr int OUTW  = T_LEN - GAP_;     // 8185
constexpr int NP    = T_LEN - 1;        // 8191
constexpr int NTHR  = 512;
constexpr int CH    = 16;               // outputs per thread
constexpr int ROWF  = OUTW * 2;         // 16370 floats per output row
constexpr int SEGF  = 8192;             // floats per segment (4096 outputs)

typedef float v2f __attribute__((ext_vector_type(2)));

__global__ __launch_bounds__(NTHR)
void forex_prep_kernel(const float* __restrict__ x, float* __restrict__ out,
                       int n_rows) {
    const int row = blockIdx.x;
    if (row >= n_rows) return;
    const int t = threadIdx.x;

    __shared__ float tile[256 * 33];    // 33 KB transpose tile (pad-1 per 32)
    __shared__ float red[NTHR / 64];

    const float* __restrict__ xr = x + (size_t)row * T_LEN;
    const int base = CH * t;

    // ---- Load x[base .. base+23] into registers (6x float4; OOB -> 1.0f).
    float xv[CH + GAP_ + 1];
#pragma unroll
    for (int q = 0; q < 6; ++q) {
        const int e = base + 4 * q;
        if (e + 3 < T_LEN) {
            const float4 v = *reinterpret_cast<const float4*>(xr + e);
            xv[4*q+0] = v.x; xv[4*q+1] = v.y; xv[4*q+2] = v.z; xv[4*q+3] = v.w;
        } else {
#pragma unroll
            for (int e2 = 0; e2 < 4; ++e2)
                xv[4*q+e2] = (e + e2 < T_LEN) ? xr[e + e2] : 1.0f;
        }
    }

    // ---- p[k] = x[base+k+1]/x[base+k] - 1, zeroed where invalid.
    float p[CH + GAP_ - 1];             // 22
#pragma unroll
    for (int k = 0; k < CH + GAP_ - 1; ++k) {
        const float pk = fmaf(xv[k + 1], __builtin_amdgcn_rcpf(xv[k]), -1.0f);
        p[k] = (base + k < NP) ? pk : 0.0f;
    }

    // ---- Block max of |p| over each thread's own share (k = 0..15).
    float m = 0.0f;
#pragma unroll
    for (int k = 0; k < CH; ++k) m = fmaxf(m, fabsf(p[k]));
#pragma unroll
    for (int off = 32; off > 0; off >>= 1)
        m = fmaxf(m, __shfl_xor(m, off, 64));
    if ((t & 63) == 0) red[t >> 6] = m;
    __syncthreads();
    float scale = red[0];
#pragma unroll
    for (int wv = 1; wv < NTHR / 64; ++wv) scale = fmaxf(scale, red[wv]);
    const float inv = __builtin_amdgcn_rcpf(scale * (float)GAP_);  // 1/(7*scale)

    // ---- Rolling 7-window sums -> ma[0..15] in registers.
    float ma[CH];
    float w = ((p[0] + p[1]) + (p[2] + p[3])) + ((p[4] + p[5]) + p[6]);
    ma[0] = w * inv;
#pragma unroll
    for (int k = 1; k < CH; ++k) {
        w += p[k + GAP_ - 1] - p[k - 1];
        ma[k] = w * inv;
    }

    // ---- Two segments: transpose through LDS, then dense NT float2 stores.
    const int my_seg = t >> 8;          // threads 0..255 own outputs [0,4096)
    const int u = t & 255;
    float* __restrict__ orow = out + (size_t)row * ROWF;

#pragma unroll
    for (int seg = 0; seg < 2; ++seg) {
        if (my_seg == seg) {
            float* tb = tile + 33 * u;  // bank = (u + c) % 32: conflict-free
#pragma unroll
            for (int k = 0; k < CH; ++k) {
                tb[2*k]     = ma[k];
                tb[2*k + 1] = xv[k];
            }
        }
        __syncthreads();                // tile ready
        const int nf = (seg == 0) ? SEGF : (ROWF - SEGF);   // 8192 / 8178
        float* __restrict__ gb = orow + seg * SEGF;
#pragma unroll
        for (int q = 0; q < 8; ++q) {
            const int L = (q * NTHR + t) * 2;   // dense even offsets
            if (L < nf) {
                const int Lp = L + (L >> 5);    // pad-1 per 32 floats
                const v2f val = {tile[Lp], tile[Lp + 1]};
                __builtin_nontemporal_store(val,
                    reinterpret_cast<v2f*>(gb + L));
            }
        }
        if (seg == 0) __syncthreads();  // copy done before seg-1 overwrite
    }
}

extern "C" void kernel_launch(void* const* d_in, const int* in_sizes, int n_in,
                              void* d_out, int out_size, void* d_ws, size_t ws_size,
                              hipStream_t stream) {
    const float* x = (const float*)d_in[0];
    float* out = (float*)d_out;
    const int n_rows = in_sizes[0] / T_LEN;   // 4096
    dim3 grid(n_rows), block(NTHR);
    hipLaunchKernelGGL(forex_prep_kernel, grid, block, 0, stream, x, out, n_rows);
}